// Round 6
// baseline (1322.464 us; speedup 1.0000x reference)
//
#include <hip/hip_runtime.h>
#include <hip/hip_bf16.h>
#include <math.h>

#define D 128

// problem sizes (fixed by reference)
#define NU 100000
#define NP 100000
#define NC 1000
#define NB 2000
#define NTOT 203000
#define EB 100000
#define ES 50000
#define ETOT 800000
#define NSEG 803000
#define NBLK 785          // ceil(NSEG/1024)

// ws layout (float offsets)
#define OFF_L    0            // 6448000 floats: low-rank accumulators
#define OFF_W0   6448000      // 10*3*128
#define OFF_BS   6451840      // 16 (bs[4])
#define OFF_WT   7251856      // 16384 floats: W_base^T
#define OFF_AT   7268240      // 8192 floats: A^T per phi
#define OFF_INT  7276432      // int region
// ints relative to (int*)(wsf+OFF_INT):
//   counts @ 0        (803000)
//   starts @ 803000   (803000)  -- after kscatter: segment END
//   srco   @ 1606000  (800000)  -- src | o<<17 | et<<19, CSR order
// bsums (785 ints) overlays OFF_L (only used before kagg rewrites L)

// per-edge-type metadata
__constant__ int c_srcT[10]   = {0,0,0,1,1,1,1,2,1,3};
__constant__ int c_phi [10]   = {0,0,0,1,1,1,1,2,1,3};
__constant__ int c_beta[10]   = {0,1,2,0,1,2,-1,-1,-1,-1};
__constant__ int c_E   [10]   = {EB,EB,EB,EB,EB,EB,ES,ES,ES,ES};
__constant__ int c_moff[10]   = {0,100000,200000,300000,400000,500000,600000,601000,701000,703000};

// per-dst-type gather config
__constant__ int g_nEt[4]     = {3,5,1,1};
__constant__ int g_ets[4][5]  = {{3,4,5,0,0},{0,1,2,7,9},{6,0,0,0,0},{8,0,0,0,0}};
__constant__ int g_gidx[4][5] = {{0,0,0,0,0},{0,0,0,1,2},{0,0,0,0,0},{0,0,0,0,0}};
__constant__ int g_nGrp[4]    = {1,3,1,1};
__constant__ int g_Loff[4][3] = {{1600000,0,0},{0,3216000,4848000},{3200000,0,0},{4816000,0,0}};
__constant__ int g_ai[4][3]   = {{1,0,0},{0,2,3},{1,0,0},{1,0,0}};

// k4 fused-launch block ranges: U 782, P 782, C 8, B 16
#define K4_BU 782
#define K4_BP 1564
#define K4_BC 1572
#define K4_BT 1588

struct Ptrs {
    const float* x[4];
    const int*   ei[10];
    const int*   attr[4];   // for edge types 6..9
};

__device__ __forceinline__ void decode_et(int eflat, int& et, int& le) {
    if (eflat < 600000) { et = eflat / 100000; le = eflat - et * 100000; }
    else { int r = eflat - 600000; int q = r / 50000; et = 6 + q; le = r - q * 50000; }
}

// sum across the 16-lane quarter-wave group
__device__ __forceinline__ float qsum(float v) {
    v += __shfl_xor(v, 1, 64);
    v += __shfl_xor(v, 2, 64);
    v += __shfl_xor(v, 4, 64);
    v += __shfl_xor(v, 8, 64);
    return v;
}

// ---------------- K0: w0 tables + bs (softmax-invariant terms dropped) ----------------
__global__ void k0_tables(const float* __restrict__ Wb, const float* __restrict__ A,
                          const float* __restrict__ B, const float* __restrict__ behW,
                          const float* __restrict__ a_att,
                          float* __restrict__ w0, float* __restrict__ bs_out)
{
    __shared__ float a0[128];
    __shared__ float c0[128];
    __shared__ float g0[4][16];
    int t = threadIdx.x;
    if (t < 128) a0[t] = a_att[t];
    __syncthreads();
    if (t < 128) {
        float s0=0.f;
        for (int j=0;j<128;j++) s0 += Wb[j*128+t]*a0[j];
        c0[t]=s0;
    } else if (t < 192) {
        int q=t-128, p=q>>4, r=q&15;
        float s0=0.f;
        for (int i=0;i<128;i++) s0 += A[p*2048+i*16+r]*a0[i];
        g0[p][r]=s0;
    } else if (t < 196) {
        int b=t-192; float s=0.f;
        for (int i=0;i<128;i++) s += behW[b*128+i]*a_att[384+i];
        bs_out[b]=s;
    }
    __syncthreads();
    if (t < 128) {
        for (int et=0; et<10; ++et) {
            int phi=c_phi[et], beta=c_beta[et];
            if (beta >= 0) {
                float s0=c0[t];
                for (int r=0;r<16;r++) s0 += B[beta*2048+t*16+r]*g0[phi][r];
                w0[et*384+t]=s0; w0[et*384+128+t]=s0; w0[et*384+256+t]=s0;
            } else {
                for (int o=0;o<3;o++){
                    float s0=c0[t];
                    for (int r=0;r<16;r++) s0 += B[o*2048+t*16+r]*g0[phi][r];
                    w0[et*384+o*128+t]=s0;
                }
            }
        }
    }
}

// ---------------- ktrans: W_base^T and A^T precompute ----------------
__global__ __launch_bounds__(256) void ktrans(const float* __restrict__ Wb,
        const float* __restrict__ A, float* __restrict__ WbT, float* __restrict__ AT)
{
    int idx = blockIdx.x*256 + threadIdx.x;
    if (idx < 16384) { int i = idx>>7, j = idx&127; WbT[i*128+j] = Wb[j*128+i]; }
    int idx2 = idx - 16384;
    if (idx2 >= 0 && idx2 < 8192) {
        int p = idx2>>11, rem = idx2&2047, r = rem>>7, j = rem&127;
        AT[idx2] = A[p*2048 + j*16 + r];
    }
}

// ---------------- CSR build ----------------
__global__ __launch_bounds__(256) void khist(Ptrs P, int* __restrict__ counts)
{
    int eflat = blockIdx.x*256 + threadIdx.x;
    if (eflat >= ETOT) return;
    int et, le; decode_et(eflat, et, le);
    int dst = P.ei[et][c_E[et] + le];
    atomicAdd(&counts[c_moff[et] + dst], 1);
}

__global__ __launch_bounds__(256) void kscan1(const int* __restrict__ cnt,
                                              int* __restrict__ st, int* __restrict__ bsums)
{
    __shared__ int lds[256];
    int t = threadIdx.x, b = blockIdx.x;
    int base = b*1024 + t*4;
    int v0 = (base   < NSEG) ? cnt[base]   : 0;
    int v1 = (base+1 < NSEG) ? cnt[base+1] : 0;
    int v2 = (base+2 < NSEG) ? cnt[base+2] : 0;
    int v3 = (base+3 < NSEG) ? cnt[base+3] : 0;
    int s = v0+v1+v2+v3;
    lds[t] = s; __syncthreads();
    for (int off=1; off<256; off<<=1){
        int xv = (t>=off) ? lds[t-off] : 0;
        __syncthreads();
        lds[t] += xv;
        __syncthreads();
    }
    int incl = lds[t];
    int p = incl - s;
    if (t==255) bsums[b] = incl;
    if (base   < NSEG) st[base]   = p; p += v0;
    if (base+1 < NSEG) st[base+1] = p; p += v1;
    if (base+2 < NSEG) st[base+2] = p; p += v2;
    if (base+3 < NSEG) st[base+3] = p;
}

__global__ __launch_bounds__(256) void kscan2(int* __restrict__ bsums)
{
    __shared__ int lds[256];
    int t = threadIdx.x;
    int base = t*4;
    int v0 = (base   < NBLK) ? bsums[base]   : 0;
    int v1 = (base+1 < NBLK) ? bsums[base+1] : 0;
    int v2 = (base+2 < NBLK) ? bsums[base+2] : 0;
    int v3 = (base+3 < NBLK) ? bsums[base+3] : 0;
    int s = v0+v1+v2+v3;
    lds[t] = s; __syncthreads();
    for (int off=1; off<256; off<<=1){
        int xv = (t>=off) ? lds[t-off] : 0;
        __syncthreads();
        lds[t] += xv;
        __syncthreads();
    }
    int p = lds[t] - s;
    if (base   < NBLK) bsums[base]   = p; p += v0;
    if (base+1 < NBLK) bsums[base+1] = p; p += v1;
    if (base+2 < NBLK) bsums[base+2] = p; p += v2;
    if (base+3 < NBLK) bsums[base+3] = p;
}

__global__ __launch_bounds__(256) void kscan3(int* __restrict__ st, const int* __restrict__ bsums)
{
    int t = threadIdx.x, b = blockIdx.x;
    int add = bsums[b];
    int base = b*1024 + t*4;
    #pragma unroll
    for (int j=0;j<4;j++)
        if (base+j < NSEG) st[base+j] += add;
}

__global__ __launch_bounds__(256) void kscatter(Ptrs P, int* __restrict__ st, int* __restrict__ srco)
{
    int eflat = blockIdx.x*256 + threadIdx.x;
    if (eflat >= ETOT) return;
    int et, le; decode_et(eflat, et, le);
    const int* ei = P.ei[et];
    int E = c_E[et];
    int src = ei[le], dst = ei[E+le];
    int o = 0;
    if (et >= 6) { int a = P.attr[et-6][le]; o = min(max(a,0),2); }
    int pos = atomicAdd(&st[c_moff[et] + dst], 1);
    srco[pos] = src | (o<<17) | (et<<19);
}
// after kscatter: st[seg] == segment end; start = st[seg] - counts[seg]

// ---------------- kagg: one WAVE per node; no-max softmax, deep prefetch ----------------
// lane = 64-lane wave lane; grp = lane>>4 (edge slot 0..3); ln = lane&15 (feature chunk)
__global__ __launch_bounds__(256) void kagg(Ptrs P,
        const int* __restrict__ starts, const int* __restrict__ counts,
        const int* __restrict__ srco,
        const float* __restrict__ w0, const float* __restrict__ bs,
        const float* __restrict__ Bm,
        float* __restrict__ Sout, float* __restrict__ Lb, int nWaves)
{
    int lane = threadIdx.x & 63;
    int wv = (blockIdx.x * 256 + threadIdx.x) >> 6;
    int grp = lane >> 4, ln = lane & 15;
    float bs0 = bs[0], bs1 = bs[1], bs2 = bs[2];

    for (int nid = wv; nid < NTOT; nid += nWaves) {
        int T, n0;
        if (nid < NU) { T=0; n0=nid; }
        else if (nid < 200000) { T=1; n0=nid-100000; }
        else if (nid < 201000) { T=2; n0=nid-200000; }
        else { T=3; n0=nid-201000; }
        int nEt = g_nEt[T];

        // ---- upfront parallel seginfo loads (all segments of this node)
        int cnt_[5], st0_[5];
        #pragma unroll
        for (int s=0;s<5;s++){ cnt_[s]=0; st0_[s]=0; }
        #pragma unroll
        for (int s=0;s<5;s++){
            if (s < nEt) {
                int seg = c_moff[g_ets[T][s]] + n0;
                int c = counts[seg];
                st0_[s] = starts[seg] - c;
                cnt_[s] = c;
            }
        }
        // ---- upfront parallel srco quad-0 loads
        int sv_[5];
        #pragma unroll
        for (int s=0;s<5;s++){
            sv_[s] = 0;
            if (s < nEt && grp < cnt_[s]) sv_[s] = srco[st0_[s] + grp];
        }
        // ---- prefetch x quad-0 for segment 0
        float4 pA = make_float4(0.f,0.f,0.f,0.f), pB = pA;
        if (nEt > 0 && grp < cnt_[0]) {
            const float* q = P.x[c_srcT[g_ets[T][0]]] + (sv_[0] & 0x1FFFF)*D + ln*8;
            pA = *(const float4*)q; pB = *(const float4*)(q+4);
        }

        float Stot[8] = {0,0,0,0,0,0,0,0};
        float L0q[4] = {0,0,0,0}, L1q[4] = {0,0,0,0}, L2q[4] = {0,0,0,0};

        #pragma unroll
        for (int s=0;s<5;s++){
            if (s < nEt) {
                int et = g_ets[T][s];
                int cnt = cnt_[s], st0 = st0_[s];
                float4 cA = pA, cB = pB;
                int svq = sv_[s];
                // rolling prefetch: next segment's quad-0 x
                pA = make_float4(0.f,0.f,0.f,0.f); pB = pA;
                if (s+1 < nEt && grp < cnt_[s+1]) {
                    const float* qn = P.x[c_srcT[g_ets[T][s+1]]] + (sv_[s+1] & 0x1FFFF)*D + ln*8;
                    pA = *(const float4*)qn; pB = *(const float4*)(qn+4);
                }
                if (cnt > 0) {
                    bool structural = (et >= 6);
                    const float* xs = P.x[c_srcT[et]];
                    const float* wp = w0 + et*384 + ln*8;
                    float4 wAb, wBb;
                    if (!structural) { wAb = *(const float4*)wp; wBb = *(const float4*)(wp+4); }

                    float ssum = 0.f;
                    float SA[8]={0,0,0,0,0,0,0,0}, SB[8]={0,0,0,0,0,0,0,0}, SC[8]={0,0,0,0,0,0,0,0};
                    int fB=0, fC=0;

                    for (int k0=0; k0<cnt; k0+=4){
                        // prefetch next quad (srco -> x)
                        int svn = 0;
                        float4 nA = make_float4(0.f,0.f,0.f,0.f), nB = nA;
                        if (k0+4+grp < cnt) {
                            svn = srco[st0+k0+4+grp];
                            const float* qn = xs + (svn & 0x1FFFF)*D + ln*8;
                            nA = *(const float4*)qn; nB = *(const float4*)(qn+4);
                        }
                        bool act = (k0+grp) < cnt;
                        int o = (svq>>17)&3;
                        float4 wA, wB;
                        if (structural) {
                            const float* wq = wp + o*128;
                            wA = *(const float4*)wq; wB = *(const float4*)(wq+4);
                        } else { wA = wAb; wB = wBb; }
                        float d = cA.x*wA.x + cA.y*wA.y + cA.z*wA.z + cA.w*wA.w
                                + cB.x*wB.x + cB.y*wB.y + cB.z*wB.z + cB.w*wB.w;
                        d = qsum(d);   // e, replicated over the slot's 16 lanes
                        float h[8] = {cA.x,cA.y,cA.z,cA.w,cB.x,cB.y,cB.z,cB.w};
                        if (structural) {
                            float bsel = (o==0) ? bs0 : ((o==1) ? bs1 : bs2);
                            float wg = act ? __expf(d + bsel) : 0.f;
                            ssum += wg;
                            float wg0 = (o==0)?wg:0.f, wg1 = (o==1)?wg:0.f, wg2 = (o==2)?wg:0.f;
                            fB |= (int)(act && (o==1));
                            fC |= (int)(act && (o==2));
                            #pragma unroll
                            for (int j=0;j<8;j++){
                                SA[j] += wg0*h[j];
                                SB[j] += wg1*h[j];
                                SC[j] += wg2*h[j];
                            }
                        } else {
                            float wg = act ? __expf(d) : 0.f;
                            ssum += wg;
                            #pragma unroll
                            for (int j=0;j<8;j++) SA[j] += wg*h[j];
                        }
                        svq = svn; cA = nA; cB = nB;
                    }

                    // total ssum across slots (wg uniform within slot)
                    float stt = ssum;
                    stt += __shfl_xor(stt, 16, 64);
                    stt += __shfl_xor(stt, 32, 64);
                    float inv = 1.f/(stt + 1e-16f);

                    // cross-slot reduce buckets (zeros stay zero if bucket unused)
                    #pragma unroll
                    for (int j=0;j<8;j++){ SA[j] += __shfl_xor(SA[j],16,64); SA[j] += __shfl_xor(SA[j],32,64); }
                    int anyB = 0, anyC = 0;
                    if (structural) {
                        anyB = __any(fB); anyC = __any(fC);
                        if (anyB) {
                            #pragma unroll
                            for (int j=0;j<8;j++){ SB[j] += __shfl_xor(SB[j],16,64); SB[j] += __shfl_xor(SB[j],32,64); }
                        }
                        if (anyC) {
                            #pragma unroll
                            for (int j=0;j<8;j++){ SC[j] += __shfl_xor(SC[j],16,64); SC[j] += __shfl_xor(SC[j],32,64); }
                        }
                    }

                    // B^T (rows ln*8..+7, cols grp*4..+3), then normalize
                    float pr[4] = {0.f,0.f,0.f,0.f};
                    if (structural) {
                        #pragma unroll
                        for (int j=0;j<8;j++)
                            Stot[j] += (SA[j] + SB[j] + SC[j]) * inv;
                        {
                            const float* Bp = Bm + grp*4;
                            #pragma unroll
                            for (int j=0;j<8;j++){
                                float4 b4 = *(const float4*)(Bp + (ln*8+j)*16);
                                pr[0]+=SA[j]*b4.x; pr[1]+=SA[j]*b4.y; pr[2]+=SA[j]*b4.z; pr[3]+=SA[j]*b4.w;
                            }
                        }
                        if (anyB) {
                            const float* Bp = Bm + 2048 + grp*4;
                            #pragma unroll
                            for (int j=0;j<8;j++){
                                float4 b4 = *(const float4*)(Bp + (ln*8+j)*16);
                                pr[0]+=SB[j]*b4.x; pr[1]+=SB[j]*b4.y; pr[2]+=SB[j]*b4.z; pr[3]+=SB[j]*b4.w;
                            }
                        }
                        if (anyC) {
                            const float* Bp = Bm + 4096 + grp*4;
                            #pragma unroll
                            for (int j=0;j<8;j++){
                                float4 b4 = *(const float4*)(Bp + (ln*8+j)*16);
                                pr[0]+=SC[j]*b4.x; pr[1]+=SC[j]*b4.y; pr[2]+=SC[j]*b4.z; pr[3]+=SC[j]*b4.w;
                            }
                        }
                    } else {
                        #pragma unroll
                        for (int j=0;j<8;j++) Stot[j] += SA[j] * inv;
                        int beta = c_beta[et];
                        const float* Bp = Bm + beta*2048 + grp*4;
                        #pragma unroll
                        for (int j=0;j<8;j++){
                            float4 b4 = *(const float4*)(Bp + (ln*8+j)*16);
                            pr[0]+=SA[j]*b4.x; pr[1]+=SA[j]*b4.y; pr[2]+=SA[j]*b4.z; pr[3]+=SA[j]*b4.w;
                        }
                    }
                    #pragma unroll
                    for (int q=0;q<4;q++) pr[q] = qsum(pr[q]) * inv;

                    int gi = g_gidx[T][s];
                    if (gi == 0) { L0q[0]+=pr[0]; L0q[1]+=pr[1]; L0q[2]+=pr[2]; L0q[3]+=pr[3]; }
                    else if (gi == 1) { L1q[0]+=pr[0]; L1q[1]+=pr[1]; L1q[2]+=pr[2]; L1q[3]+=pr[3]; }
                    else { L2q[0]+=pr[0]; L2q[1]+=pr[1]; L2q[2]+=pr[2]; L2q[3]+=pr[3]; }
                }
            }
        }

        if (grp == 0) {
            float* Srow = Sout + (size_t)nid*D + ln*8;
            *(float4*)Srow     = make_float4(Stot[0],Stot[1],Stot[2],Stot[3]);
            *(float4*)(Srow+4) = make_float4(Stot[4],Stot[5],Stot[6],Stot[7]);
        }
        if (ln < 4) {
            float v0 = (ln==0)?L0q[0]:(ln==1)?L0q[1]:(ln==2)?L0q[2]:L0q[3];
            Lb[g_Loff[T][0] + (size_t)n0*16 + grp*4 + ln] = v0;
            int ng = g_nGrp[T];
            if (ng > 1) {
                float v1 = (ln==0)?L1q[0]:(ln==1)?L1q[1]:(ln==2)?L1q[2]:L1q[3];
                Lb[g_Loff[T][1] + (size_t)n0*16 + grp*4 + ln] = v1;
            }
            if (ng > 2) {
                float v2 = (ln==0)?L2q[0]:(ln==1)?L2q[1]:(ln==2)?L2q[2]:L2q[3];
                Lb[g_Loff[T][2] + (size_t)n0*16 + grp*4 + ln] = v2;
            }
        }
    }
}

// ---------------- K4 (fused): agg = W_base@S + sum A[p]@L_p, LN+ELU+residual ----------
__global__ __launch_bounds__(512, 1) void k4_final(Ptrs P,
        const float* __restrict__ WbT, const float* __restrict__ AT,
        const float* __restrict__ Lb,
        const float* __restrict__ gamma, const float* __restrict__ lbeta,
        float* __restrict__ out)
{
    __shared__ float st[128*132];   // S tile, stride 132
    __shared__ float wt[128*128];   // WbT tile: wt[i*128 + j]
    __shared__ float lt[128*52];    // L tile: lt[r*52 + pi*16 + k]
    int t = threadIdx.x;
    int b = blockIdx.x;
    int T, lb;
    if (b < K4_BU)      { T=0; lb=b; }
    else if (b < K4_BP) { T=1; lb=b-K4_BU; }
    else if (b < K4_BC) { T=2; lb=b-K4_BP; }
    else                { T=3; lb=b-K4_BC; }
    int r0 = lb*128;
    int rowStart = (T==0)?0:((T==1)?100000:((T==2)?200000:201000));
    int nRows    = (T==0)?NU:((T==1)?NP:((T==2)?NC:NB));
    const float* x = P.x[T];
    int nPairs = g_nGrp[T];

    for (int idx=t; idx<4096; idx+=512)
        *(float4*)&wt[idx*4] = *(const float4*)&WbT[idx*4];
    for (int idx=t; idx<4096; idx+=512){
        int r = idx>>5, i4 = idx&31;
        int lr = r0 + r;
        float4 v = (lr < nRows) ? *(const float4*)&out[(size_t)(rowStart+lr)*D + i4*4]
                                : make_float4(0.f,0.f,0.f,0.f);
        *(float4*)&st[r*132 + i4*4] = v;
    }
    for (int pi=0; pi<nPairs; ++pi){
        int lo = g_Loff[T][pi];
        int r = t>>2, q = t&3;
        int lr = r0 + r;
        float4 v = (lr < nRows) ? *(const float4*)&Lb[lo + (size_t)lr*16 + q*4]
                                : make_float4(0.f,0.f,0.f,0.f);
        *(float4*)&lt[r*52 + pi*16 + q*4] = v;
    }
    __syncthreads();

    int cg = t & 15, rg = t >> 4;
    float acc[4][8];
    #pragma unroll
    for (int a=0;a<4;a++)
        #pragma unroll
        for (int c=0;c<8;c++) acc[a][c]=0.f;

    for (int i4=0; i4<32; ++i4){
        float4 sv0 = *(const float4*)&st[(rg*4+0)*132 + i4*4];
        float4 sv1 = *(const float4*)&st[(rg*4+1)*132 + i4*4];
        float4 sv2 = *(const float4*)&st[(rg*4+2)*132 + i4*4];
        float4 sv3 = *(const float4*)&st[(rg*4+3)*132 + i4*4];
        #pragma unroll
        for (int q=0;q<4;q++){
            float4 wA = *(const float4*)&wt[(i4*4+q)*128 + cg*4];
            float4 wB = *(const float4*)&wt[(i4*4+q)*128 + 64 + cg*4];
            float sq[4];
            sq[0] = (q==0)?sv0.x:(q==1)?sv0.y:(q==2)?sv0.z:sv0.w;
            sq[1] = (q==0)?sv1.x:(q==1)?sv1.y:(q==2)?sv1.z:sv1.w;
            sq[2] = (q==0)?sv2.x:(q==1)?sv2.y:(q==2)?sv2.z:sv2.w;
            sq[3] = (q==0)?sv3.x:(q==1)?sv3.y:(q==2)?sv3.z:sv3.w;
            #pragma unroll
            for (int rr=0;rr<4;rr++){
                acc[rr][0] += sq[rr]*wA.x;
                acc[rr][1] += sq[rr]*wA.y;
                acc[rr][2] += sq[rr]*wA.z;
                acc[rr][3] += sq[rr]*wA.w;
                acc[rr][4] += sq[rr]*wB.x;
                acc[rr][5] += sq[rr]*wB.y;
                acc[rr][6] += sq[rr]*wB.z;
                acc[rr][7] += sq[rr]*wB.w;
            }
        }
    }

    for (int pi=0; pi<nPairs; ++pi){
        int ai = g_ai[T][pi];
        const float* Ap = AT + ai*2048;
        #pragma unroll 4
        for (int r=0;r<16;++r){
            float4 aA = *(const float4*)&Ap[r*128 + cg*4];
            float4 aB = *(const float4*)&Ap[r*128 + 64 + cg*4];
            float lv[4];
            #pragma unroll
            for (int rr=0;rr<4;rr++) lv[rr] = lt[(rg*4+rr)*52 + pi*16 + r];
            #pragma unroll
            for (int rr=0;rr<4;rr++){
                acc[rr][0] += lv[rr]*aA.x;
                acc[rr][1] += lv[rr]*aA.y;
                acc[rr][2] += lv[rr]*aA.z;
                acc[rr][3] += lv[rr]*aA.w;
                acc[rr][4] += lv[rr]*aB.x;
                acc[rr][5] += lv[rr]*aB.y;
                acc[rr][6] += lv[rr]*aB.z;
                acc[rr][7] += lv[rr]*aB.w;
            }
        }
    }

    int jA = cg*4, jB = 64 + cg*4;
    float4 gA = *(const float4*)&gamma[jA], gB = *(const float4*)&gamma[jB];
    float4 bA = *(const float4*)&lbeta[jA], bB = *(const float4*)&lbeta[jB];
    float gv[8] = {gA.x,gA.y,gA.z,gA.w,gB.x,gB.y,gB.z,gB.w};
    float bv[8] = {bA.x,bA.y,bA.z,bA.w,bB.x,bB.y,bB.z,bB.w};

    #pragma unroll
    for (int rr=0;rr<4;rr++){
        int lr = r0 + rg*4 + rr;
        float lsum=0.f, lsq=0.f;
        #pragma unroll
        for (int c=0;c<8;c++){ lsum += acc[rr][c]; lsq += acc[rr][c]*acc[rr][c]; }
        #pragma unroll
        for (int mm=1; mm<16; mm<<=1){ lsum += __shfl_xor(lsum,mm,64); lsq += __shfl_xor(lsq,mm,64); }
        if (lr >= nRows) continue;
        float mu = lsum*(1.f/128.f);
        float var = lsq*(1.f/128.f) - mu*mu;
        float rstd = rsqrtf(var + 1e-5f);
        const float* xr = x + (size_t)lr*D;
        float4 xA = *(const float4*)(xr+jA), xB = *(const float4*)(xr+jB);
        float xv[8] = {xA.x,xA.y,xA.z,xA.w,xB.x,xB.y,xB.z,xB.w};
        float ov[8];
        #pragma unroll
        for (int c=0;c<8;c++){
            float hn = (acc[rr][c]-mu)*rstd*gv[c] + bv[c];
            float z = hn + xv[c];
            ov[c] = z > 0.f ? z : expm1f(z);
        }
        float* orow = out + (size_t)(rowStart+lr)*D;
        *(float4*)(orow+jA) = make_float4(ov[0],ov[1],ov[2],ov[3]);
        *(float4*)(orow+jB) = make_float4(ov[4],ov[5],ov[6],ov[7]);
    }
}

extern "C" void kernel_launch(void* const* d_in, const int* in_sizes, int n_in,
                              void* d_out, int out_size, void* d_ws, size_t ws_size,
                              hipStream_t stream)
{
    (void)in_sizes; (void)n_in; (void)out_size; (void)ws_size;
    Ptrs P;
    P.x[0] = (const float*)d_in[0];   // x_user
    P.x[1] = (const float*)d_in[1];   // x_product
    P.x[2] = (const float*)d_in[2];   // x_category
    P.x[3] = (const float*)d_in[3];   // x_brand
    P.ei[0] = (const int*)d_in[4];    // view
    P.ei[1] = (const int*)d_in[5];    // cart
    P.ei[2] = (const int*)d_in[6];    // purchase
    P.ei[3] = (const int*)d_in[7];    // rev_view
    P.ei[4] = (const int*)d_in[8];    // rev_cart
    P.ei[5] = (const int*)d_in[9];    // rev_purchase
    P.ei[6] = (const int*)d_in[10];   // belongs_to
    P.attr[0] = (const int*)d_in[11];
    P.ei[7] = (const int*)d_in[12];   // contains
    P.attr[1] = (const int*)d_in[13];
    P.ei[8] = (const int*)d_in[14];   // producedBy
    P.attr[2] = (const int*)d_in[15];
    P.ei[9] = (const int*)d_in[16];   // brands
    P.attr[3] = (const int*)d_in[17];
    const float* Wb    = (const float*)d_in[18];
    const float* A     = (const float*)d_in[19];
    const float* B     = (const float*)d_in[20];
    const float* behW  = (const float*)d_in[22];
    const float* a_att = (const float*)d_in[23];
    const float* gamma = (const float*)d_in[24];
    const float* lbeta = (const float*)d_in[25];
    float* wsf = (float*)d_ws;
    float* out = (float*)d_out;

    int* ip     = (int*)(wsf + OFF_INT);
    int* counts = ip;
    int* starts = ip + 803000;
    int* srco   = ip + 1606000;
    int* bsums  = (int*)wsf;          // overlays L region, used only pre-kagg

    hipMemsetAsync(counts, 0, (size_t)NSEG*sizeof(int), stream);

    k0_tables<<<1, 256, 0, stream>>>(Wb, A, B, behW, a_att, wsf+OFF_W0, wsf+OFF_BS);
    ktrans<<<96, 256, 0, stream>>>(Wb, A, wsf+OFF_WT, wsf+OFF_AT);
    khist<<<3125, 256, 0, stream>>>(P, counts);
    kscan1<<<NBLK, 256, 0, stream>>>(counts, starts, bsums);
    kscan2<<<1, 256, 0, stream>>>(bsums);
    kscan3<<<NBLK, 256, 0, stream>>>(starts, bsums);
    kscatter<<<3125, 256, 0, stream>>>(P, starts, srco);

    kagg<<<2048, 256, 0, stream>>>(P, starts, counts, srco,
                                   wsf+OFF_W0, wsf+OFF_BS, B,
                                   out, wsf+OFF_L, 2048*4);

    k4_final<<<K4_BT, 512, 0, stream>>>(P, wsf+OFF_WT, wsf+OFF_AT, wsf+OFF_L,
                                        gamma, lbeta, out);
}